// Round 3
// baseline (801.527 us; speedup 1.0000x reference)
//
#include <hip/hip_runtime.h>
#include <stdint.h>

#define NG   64
#define NPG  4096
#define HD   256
#define NC0  256
#define NC1  64
#define KSPLIT 4
#define G_MAX 16

typedef __attribute__((ext_vector_type(8))) short bfx8;   // 8 bf16 (4 VGPRs)
typedef __attribute__((ext_vector_type(4))) float fx4;    // MFMA acc

__device__ __forceinline__ unsigned short f2bf(float f) {
  union { float f; unsigned int u; } v; v.f = f;
  return (unsigned short)((v.u + 0x7FFFu + ((v.u >> 16) & 1u)) >> 16);  // RNE
}
__device__ __forceinline__ unsigned int pack2(float a, float b) {
  return (unsigned int)f2bf(a) | ((unsigned int)f2bf(b) << 16);
}

// async global->LDS, 16B per lane; LDS dest = wave-uniform base + lane*16
#define ASYNC_COPY16(gptr, lptr) \
  __builtin_amdgcn_global_load_lds((const __attribute__((address_space(1))) unsigned int*)(gptr), \
                                   (__attribute__((address_space(3))) unsigned int*)(lptr), 16, 0, 0)

// ---------------- W0 (fp32 [h][c]) -> W0T (bf16 [c][h]) ----------------
__global__ __launch_bounds__(256) void k_w0t(const float* __restrict__ W0,
                                             unsigned short* __restrict__ W0T) {
  int idx = blockIdx.x * 256 + threadIdx.x;   // idx = c*256 + h
  int c = idx >> 8, h = idx & 255;
  W0T[idx] = f2bf(W0[h * 256 + c]);
}

// ---------------- k_xt: x fp32 [node][h] -> xb bf16 [node][h] AND xT bf16 [h][node] ----------------
// one block = 64-node tile of one graph
__global__ __launch_bounds__(256, 4) void k_xt(const float* __restrict__ x,
                                               unsigned short* __restrict__ xb,
                                               unsigned short* __restrict__ xT, int g0) {
  __shared__ unsigned short tile[64 * 256];   // [node][h] bf16, 32 KB
  int gl = blockIdx.x >> 6, ntile = blockIdx.x & 63;
  int t = threadIdx.x;
  size_t gbase = ((size_t)(g0 + gl) * NPG + (size_t)ntile * 64) * HD;

  // load fp32 coalesced, convert, store LDS (uint2 = 4 bf16)
  #pragma unroll
  for (int i = 0; i < 16; ++i) {
    int flat = t + i * 256;            // float4 index
    int row = flat >> 6, f4 = flat & 63;
    float4 v = *(const float4*)(x + gbase + (size_t)row * HD + f4 * 4);
    uint2 p;
    p.x = pack2(v.x, v.y); p.y = pack2(v.z, v.w);
    *(uint2*)(tile + row * 256 + f4 * 4) = p;
  }
  __syncthreads();

  // xT: thread t = column h; 2-way bank alias only (free)
  {
    unsigned int u[32];
    #pragma unroll
    for (int n = 0; n < 64; n += 2)
      u[n >> 1] = (unsigned int)tile[n * 256 + t] |
                  ((unsigned int)tile[(n + 1) * 256 + t] << 16);
    float4* dst = (float4*)(xT + ((size_t)gl * HD + t) * NPG + (size_t)ntile * 64);
    #pragma unroll
    for (int i = 0; i < 8; ++i) dst[i] = ((float4*)u)[i];
  }
  // xb: contiguous b128 reads, coalesced 16B stores
  #pragma unroll
  for (int i = 0; i < 8; ++i) {
    int flat = t + i * 256;            // 16B-granule index
    int row = flat >> 5, c16 = flat & 31;
    float4 v = *(const float4*)(tile + row * 256 + c16 * 8);
    *(float4*)(xb + ((size_t)gl * NPG + (size_t)ntile * 64 + row) * HD + c16 * 8) = v;
  }
}

// ---------------- K1: A0 = softmax(xb@W0 + b0) -> A0T bf16 [c][node] ----------------
// m97 structure: 256 thr / 4 waves, tile 64 nodes x 256 clusters, K=256 (BK=64),
// all-ASYNC staging with XOR-swizzled 16B granules. Wave wn covers clusters wn*64..+63.
__global__ __launch_bounds__(256, 3) void k_assign0(
    const unsigned short* __restrict__ xb, const unsigned short* __restrict__ W0T,
    const float* __restrict__ b0, unsigned short* __restrict__ A0T) {
  __shared__ char smem[40960];                 // a_s[64][64] (8K) + b_s[256][64] (32K); alias at[256][72]
  __shared__ float red[64 * 4];
  unsigned short* a_s = (unsigned short*)smem;
  unsigned short* b_s = (unsigned short*)(smem + 8192);
  unsigned short* at  = (unsigned short*)smem;

  int gl = blockIdx.x >> 6, ntile = blockIdx.x & 63;
  int tid = threadIdx.x;
  int wave = tid >> 6, lane = tid & 63;
  int wn = wave;
  int l15 = lane & 15, q = lane >> 4;
  int srow = lane >> 3, sg = (lane & 7) ^ srow;   // staging: 8 rows/instr, swizzled granule

  const unsigned short* xbase = xb + ((size_t)gl * NPG + (size_t)ntile * 64) * HD;

  fx4 acc[4][4];
  #pragma unroll
  for (int i = 0; i < 4; ++i)
    #pragma unroll
    for (int j = 0; j < 4; ++j) acc[i][j] = fx4{0.f, 0.f, 0.f, 0.f};

  for (int kc = 0; kc < 4; ++kc) {
    int k0 = kc * 64;
    #pragma unroll
    for (int i = 0; i < 2; ++i) {   // A: 64 rows total, 2 instr/wave
      int r0 = wave * 16 + i * 8;
      ASYNC_COPY16(xbase + (size_t)(r0 + srow) * HD + k0 + sg * 8, &a_s[r0 * 64]);
    }
    #pragma unroll
    for (int i = 0; i < 8; ++i) {   // B: 256 rows total, 8 instr/wave
      int c0 = wave * 64 + i * 8;
      ASYNC_COPY16(W0T + (size_t)(c0 + srow) * HD + k0 + sg * 8, &b_s[c0 * 64]);
    }
    __syncthreads();
    #pragma unroll
    for (int ks = 0; ks < 2; ++ks) {
      int gx = ((ks * 4 + q) ^ (l15 & 7)) << 3;
      bfx8 af[4], bf[4];
      #pragma unroll
      for (int mi = 0; mi < 4; ++mi)
        af[mi] = *(const bfx8*)&a_s[(mi * 16 + l15) * 64 + gx];
      #pragma unroll
      for (int ni = 0; ni < 4; ++ni)
        bf[ni] = *(const bfx8*)&b_s[(wn * 64 + ni * 16 + l15) * 64 + gx];
      #pragma unroll
      for (int ni = 0; ni < 4; ++ni)
        #pragma unroll
        for (int mi = 0; mi < 4; ++mi)
          acc[mi][ni] = __builtin_amdgcn_mfma_f32_16x16x32_bf16(af[mi], bf[ni], acc[mi][ni], 0, 0, 0);
    }
    __syncthreads();
  }

  // ---- epilogue: bias + softmax over 256 clusters per node-row ----
  // acc[mi][ni][r]: node = mi*16 + q*4 + r, cluster = wn*64 + ni*16 + l15
  float bv4[4];
  #pragma unroll
  for (int ni = 0; ni < 4; ++ni) bv4[ni] = b0[wn * 64 + ni * 16 + l15];
  #pragma unroll
  for (int mi = 0; mi < 4; ++mi)
    #pragma unroll
    for (int ni = 0; ni < 4; ++ni)
      #pragma unroll
      for (int r = 0; r < 4; ++r) acc[mi][ni][r] += bv4[ni];

  float mrow[4][4];
  #pragma unroll
  for (int mi = 0; mi < 4; ++mi)
    #pragma unroll
    for (int r = 0; r < 4; ++r) {
      float m = fmaxf(fmaxf(acc[mi][0][r], acc[mi][1][r]), fmaxf(acc[mi][2][r], acc[mi][3][r]));
      #pragma unroll
      for (int off = 1; off < 16; off <<= 1) m = fmaxf(m, __shfl_xor(m, off));
      mrow[mi][r] = m;
    }
  if (l15 == 0) {
    #pragma unroll
    for (int mi = 0; mi < 4; ++mi)
      #pragma unroll
      for (int r = 0; r < 4; ++r)
        red[(mi * 16 + q * 4 + r) * 4 + wn] = mrow[mi][r];
  }
  __syncthreads();
  #pragma unroll
  for (int mi = 0; mi < 4; ++mi)
    #pragma unroll
    for (int r = 0; r < 4; ++r) {
      float4 rv = *(const float4*)&red[(mi * 16 + q * 4 + r) * 4];
      mrow[mi][r] = fmaxf(fmaxf(rv.x, rv.y), fmaxf(rv.z, rv.w));
    }
  __syncthreads();
  float srow2[4][4];
  #pragma unroll
  for (int mi = 0; mi < 4; ++mi)
    #pragma unroll
    for (int r = 0; r < 4; ++r) {
      float s = 0.f;
      #pragma unroll
      for (int ni = 0; ni < 4; ++ni) {
        float e = __expf(acc[mi][ni][r] - mrow[mi][r]);
        acc[mi][ni][r] = e; s += e;
      }
      #pragma unroll
      for (int off = 1; off < 16; off <<= 1) s += __shfl_xor(s, off);
      srow2[mi][r] = s;
    }
  if (l15 == 0) {
    #pragma unroll
    for (int mi = 0; mi < 4; ++mi)
      #pragma unroll
      for (int r = 0; r < 4; ++r)
        red[(mi * 16 + q * 4 + r) * 4 + wn] = srow2[mi][r];
  }
  __syncthreads();
  #pragma unroll
  for (int mi = 0; mi < 4; ++mi)
    #pragma unroll
    for (int r = 0; r < 4; ++r) {
      float4 rv = *(const float4*)&red[(mi * 16 + q * 4 + r) * 4];
      float inv = 1.f / (rv.x + rv.y + rv.z + rv.w);
      #pragma unroll
      for (int ni = 0; ni < 4; ++ni) acc[mi][ni][r] *= inv;
    }
  __syncthreads();   // a_s/b_s dead; reuse as 'at' [256 c][72]

  #pragma unroll
  for (int mi = 0; mi < 4; ++mi) {
    int ncol = mi * 16 + q * 4;
    #pragma unroll
    for (int ni = 0; ni < 4; ++ni) {
      int cl = wn * 64 + ni * 16 + l15;
      uint2 w;
      w.x = pack2(acc[mi][ni][0], acc[mi][ni][1]);
      w.y = pack2(acc[mi][ni][2], acc[mi][ni][3]);
      *(uint2*)(at + cl * 72 + ncol) = w;
    }
  }
  __syncthreads();
  {   // thread t = cluster row; 64 bf16 per row -> 8x b128 reads, 8x 16B stores
    float4 v[8];
    #pragma unroll
    for (int s = 0; s < 8; ++s) v[s] = *(const float4*)(at + tid * 72 + s * 8);
    unsigned short* dst = A0T + ((size_t)gl * NC0 + tid) * NPG + (size_t)ntile * 64;
    #pragma unroll
    for (int s = 0; s < 8; ++s) *(float4*)(dst + s * 8) = v[s];
  }
}

// ---------------- K2: f0p[kidx][g][c][h] = A0T[g][c][:] . xT[g][h][:] ----------------
__global__ __launch_bounds__(256, 2) void k_pool0(
    const unsigned short* __restrict__ A0T, const unsigned short* __restrict__ xT,
    float* __restrict__ f0p, int g0) {
  __shared__ unsigned short a_s[128 * 64];
  __shared__ unsigned short b_s[128 * 64];
  int bid = blockIdx.x;
  int kidx = bid & 3;
  int nt = (bid >> 2) & 1;
  int mt = (bid >> 3) & 1;
  int gl = bid >> 4;

  int tid = threadIdx.x;
  int wave = tid >> 6, lane = tid & 63;
  int wm = wave >> 1, wn = wave & 1;
  int l15 = lane & 15, q = lane >> 4;

  const int KPER = NPG / KSPLIT;   // 1024
  const unsigned short* abase = A0T + ((size_t)gl * NC0 + (size_t)mt * 128) * NPG + (size_t)kidx * KPER;
  const unsigned short* bbase = xT  + ((size_t)gl * HD  + (size_t)nt * 128) * NPG + (size_t)kidx * KPER;

  fx4 acc[4][4];
  #pragma unroll
  for (int i = 0; i < 4; ++i)
    #pragma unroll
    for (int j = 0; j < 4; ++j) acc[i][j] = fx4{0.f, 0.f, 0.f, 0.f};

  int srow = lane >> 3;
  int sg   = (lane & 7) ^ srow;
  size_t soff = (size_t)srow * NPG + (size_t)sg * 8;

  for (int k0 = 0; k0 < KPER; k0 += 64) {
    #pragma unroll
    for (int i = 0; i < 4; ++i) {
      int r0 = wave * 32 + i * 8;
      ASYNC_COPY16(abase + (size_t)r0 * NPG + k0 + soff, &a_s[r0 * 64]);
      ASYNC_COPY16(bbase + (size_t)r0 * NPG + k0 + soff, &b_s[r0 * 64]);
    }
    __syncthreads();
    #pragma unroll
    for (int ks = 0; ks < 2; ++ks) {
      int gx = ((ks * 4 + q) ^ (l15 & 7)) << 3;
      bfx8 af[4], bf[4];
      #pragma unroll
      for (int mi = 0; mi < 4; ++mi)
        af[mi] = *(const bfx8*)&a_s[(wm * 64 + mi * 16 + l15) * 64 + gx];
      #pragma unroll
      for (int ni = 0; ni < 4; ++ni)
        bf[ni] = *(const bfx8*)&b_s[(wn * 64 + ni * 16 + l15) * 64 + gx];
      #pragma unroll
      for (int ni = 0; ni < 4; ++ni)
        #pragma unroll
        for (int mi = 0; mi < 4; ++mi)
          acc[mi][ni] = __builtin_amdgcn_mfma_f32_16x16x32_bf16(af[mi], bf[ni], acc[mi][ni], 0, 0, 0);
    }
    __syncthreads();
  }

  float* dst = f0p + (size_t)kidx * NG * NC0 * HD
             + ((size_t)(g0 + gl) * NC0 + (size_t)mt * 128) * HD + (size_t)nt * 128;
  #pragma unroll
  for (int mi = 0; mi < 4; ++mi)
    #pragma unroll
    for (int ni = 0; ni < 4; ++ni) {
      int c = wm * 64 + mi * 16 + q * 4;
      int h = wn * 64 + ni * 16 + l15;
      #pragma unroll
      for (int r = 0; r < 4; ++r)
        dst[(size_t)(c + r) * HD + h] = acc[mi][ni][r];
    }
}

// ---------------- f0 = sum of 4 partials (in place: f0 == f0p0) ----------------
__global__ __launch_bounds__(256) void k_f0sum(float* __restrict__ f0) {
  size_t i = ((size_t)blockIdx.x * 256 + threadIdx.x) * 4;
  const size_t S = (size_t)NG * NC0 * HD;
  float4 a = *(const float4*)(f0 + i);
  float4 b = *(const float4*)(f0 + S + i);
  float4 c = *(const float4*)(f0 + 2 * S + i);
  float4 d = *(const float4*)(f0 + 3 * S + i);
  a.x += b.x + c.x + d.x; a.y += b.y + c.y + d.y;
  a.z += b.z + c.z + d.z; a.w += b.w + c.w + d.w;
  *(float4*)(f0 + i) = a;
}

// ---------------- K3: A1 = softmax(f0 @ W1 + b1), wave per row ----------------
__global__ __launch_bounds__(256) void k_assign1(
    const float* __restrict__ f0, const float* __restrict__ W1,
    const float* __restrict__ b1, float* __restrict__ A1) {
  int row = blockIdx.x * 4 + (threadIdx.x >> 6);
  int lane = threadIdx.x & 63;
  const float* fr = f0 + (size_t)row * 256;
  float acc = b1[lane];
  for (int k = 0; k < 256; k += 4) {
    float4 fv = *(const float4*)(fr + k);
    acc += fv.x * W1[(k    ) * 64 + lane];
    acc += fv.y * W1[(k + 1) * 64 + lane];
    acc += fv.z * W1[(k + 2) * 64 + lane];
    acc += fv.w * W1[(k + 3) * 64 + lane];
  }
  float m = acc;
  #pragma unroll
  for (int off = 1; off < 64; off <<= 1) m = fmaxf(m, __shfl_xor(m, off));
  float e = __expf(acc - m);
  float s = e;
  #pragma unroll
  for (int off = 1; off < 64; off <<= 1) s += __shfl_xor(s, off);
  A1[(size_t)row * 64 + lane] = e / s;
}

// ---------------- K4: f1[b][c*256+h] = sum_c0 A1[b][c0][c] * f0[b][c0][h] ----------------
__global__ __launch_bounds__(256) void k_pool1(
    const float* __restrict__ A1, const float* __restrict__ f0, float* __restrict__ f1) {
  int b = blockIdx.x >> 2, cg = blockIdx.x & 3;
  int h = threadIdx.x;
  const float* a1p = A1 + (size_t)b * NC0 * NC1 + cg * 16;
  const float* f0p = f0 + (size_t)b * NC0 * HD + h;
  float acc[16];
  #pragma unroll
  for (int j = 0; j < 16; ++j) acc[j] = 0.f;
  for (int c0 = 0; c0 < 256; ++c0) {
    float fv = f0p[(size_t)c0 * 256];
    #pragma unroll
    for (int j = 0; j < 16; ++j) acc[j] += a1p[c0 * 64 + j] * fv;
  }
  float* d = f1 + (size_t)b * 16384 + (size_t)(cg * 16) * 256 + h;
  #pragma unroll
  for (int j = 0; j < 16; ++j) d[(size_t)j * 256] = acc[j];
}

// ---------------- K5a: ot[kidx][b][h] = f1[b][kidx*1024..] . Wf[..][h] ----------------
__global__ __launch_bounds__(256) void k_final_partial(
    const float* __restrict__ f1, const float* __restrict__ Wf, float* __restrict__ ot) {
  int b = blockIdx.x >> 4, kidx = blockIdx.x & 15;
  int h = threadIdx.x;
  const float* fp = f1 + (size_t)b * 16384 + (size_t)kidx * 1024;
  const float* wp = Wf + (size_t)kidx * 1024 * 256 + h;
  float acc = 0.f;
  for (int k = 0; k < 1024; k += 4) {
    float4 fv = *(const float4*)(fp + k);
    acc += fv.x * wp[(size_t)(k    ) * 256];
    acc += fv.y * wp[(size_t)(k + 1) * 256];
    acc += fv.z * wp[(size_t)(k + 2) * 256];
    acc += fv.w * wp[(size_t)(k + 3) * 256];
  }
  ot[((size_t)kidx * 64 + b) * 256 + h] = acc;
}

// ---------------- K5b: out = relu(sum_k ot + bf) ----------------
__global__ __launch_bounds__(256) void k_final_out(
    const float* __restrict__ ot, const float* __restrict__ bfv, float* __restrict__ out) {
  int b = blockIdx.x, h = threadIdx.x;
  float s = bfv[h];
  #pragma unroll
  for (int k = 0; k < 16; ++k) s += ot[((size_t)k * 64 + b) * 256 + h];
  out[b * 256 + h] = s > 0.f ? s : 0.f;
}

extern "C" void kernel_launch(void* const* d_in, const int* in_sizes, int n_in,
                              void* d_out, int out_size, void* d_ws, size_t ws_size,
                              hipStream_t stream) {
  const float* x   = (const float*)d_in[0];
  const float* W0  = (const float*)d_in[3];
  const float* b0  = (const float*)d_in[4];
  const float* W1  = (const float*)d_in[5];
  const float* b1  = (const float*)d_in[6];
  const float* Wf  = (const float*)d_in[7];
  const float* bfv = (const float*)d_in[8];
  float* out = (float*)d_out;
  char* ws = (char*)d_ws;

  // layout (bytes):
  // f0p: 4 x 16 MB @ 0 (f0 = partial 0)
  // ot: 1 MB @ 64M; W0T: 128 KB; f1: 16 MB; A1: 4 MB; ring @ ~85.3M
  float* f0p = (float*)ws;
  float* f0  = f0p;
  size_t off = (size_t)64 << 20;
  float* ot = (float*)(ws + off);                 off += (size_t)1 << 20;
  unsigned short* W0T = (unsigned short*)(ws + off); off += 131072;
  float* f1 = (float*)(ws + off);                 off += (size_t)16 << 20;
  float* A1 = (float*)(ws + off);                 off += (size_t)4 << 20;
  size_t per_graph = (size_t)3 * NPG * HD * 2;    // xb + xT + A0T = 6 MB
  size_t avail = ws_size > off ? ws_size - off : 0;
  int G = (int)(avail / per_graph);
  if (G > G_MAX) G = G_MAX;
  if (G < 1) G = 1;
  unsigned short* xb  = (unsigned short*)(ws + off);
  unsigned short* xT  = xb + (size_t)G * NPG * HD;
  unsigned short* A0T = xT + (size_t)G * NPG * HD;

  k_w0t<<<256, 256, 0, stream>>>(W0, W0T);

  for (int g0 = 0; g0 < NG; g0 += G) {
    int gc = (NG - g0 < G) ? (NG - g0) : G;
    k_xt<<<gc * 64, 256, 0, stream>>>(x, xb, xT, g0);
    k_assign0<<<gc * 64, 256, 0, stream>>>(xb, W0T, b0, A0T);
    k_pool0<<<gc * 16, 256, 0, stream>>>(A0T, xT, f0p, g0);
  }
  k_f0sum<<<4096, 256, 0, stream>>>(f0);
  k_assign1<<<4096, 256, 0, stream>>>(f0, W1, b1, A1);
  k_pool1<<<256, 256, 0, stream>>>(A1, f0, f1);
  k_final_partial<<<64 * 16, 256, 0, stream>>>(f1, Wf, ot);
  k_final_out<<<64, 256, 0, stream>>>(ot, bfv, out);
}